// Round 1
// baseline (308.259 us; speedup 1.0000x reference)
//
#include <hip/hip_runtime.h>
#include <cstdint>
#include <cstddef>

// Problem constants
#define B_N 65536
#define D_N 256
#define W_N 1024

typedef __bf16 bf16x8 __attribute__((ext_vector_type(8)));
typedef float f32x4 __attribute__((ext_vector_type(4)));
typedef unsigned short u16x8 __attribute__((ext_vector_type(8)));

__device__ __forceinline__ unsigned short f2bf(float f) {
  // round-to-nearest-even f32 -> bf16 (no NaN in this problem)
  unsigned u = __float_as_uint(f);
  u += 0x7fffu + ((u >> 16) & 1u);
  return (unsigned short)(u >> 16);
}

// ---------------------------------------------------------------------------
// Prep: cast W1 [1024x256] and W2 [256x1024] to bf16; M[j] = sum_i W1[j,i]*W2[i,j]
// ---------------------------------------------------------------------------
__global__ __launch_bounds__(256) void prep_kernel(
    const float* __restrict__ W1, const float* __restrict__ W2,
    unsigned short* __restrict__ W1b, unsigned short* __restrict__ W2b,
    float* __restrict__ M) {
  const int j = blockIdx.x;    // 0..1023
  const int t = threadIdx.x;   // 0..255
  const int gid = j * 256 + t; // covers 262144 exactly
  float w1 = W1[gid];
  float w2g = W2[gid];
  W1b[gid] = f2bf(w1);
  W2b[gid] = f2bf(w2g);
  // M[j]: thread t contributes W1[j,t] * W2[t,j]
  float p = w1 * W2[t * W_N + j];
  #pragma unroll
  for (int m = 32; m; m >>= 1) p += __shfl_xor(p, m);
  __shared__ float red[4];
  if ((t & 63) == 0) red[t >> 6] = p;
  __syncthreads();
  if (t == 0) M[j] = red[0] + red[1] + red[2] + red[3];
}

// ---------------------------------------------------------------------------
// Fused flow kernel, software-pipelined:
//   epilogue(chunk c) [VALU/trans] is interleaved with GEMM1(chunk c+1) [MFMA]
//   in one region (no barrier between them), with double-buffered acc1 (A/B,
//   static alternation via unroll-by-2 loop). GEMM2 stays a pure-MFMA phase
//   wrapped in s_setprio(1).
// LDS layouts identical to baseline (fragment-linear blocked bf16).
// ---------------------------------------------------------------------------
__global__ __launch_bounds__(256, 2) void flow_kernel(
    const float* __restrict__ z, const float* __restrict__ b1,
    const unsigned short* __restrict__ W1b, const unsigned short* __restrict__ W2b,
    const float* __restrict__ M, float* __restrict__ dz, float* __restrict__ tr) {
  __shared__ __align__(16) unsigned short z_sh[64 * 256]; // 32 KB
  __shared__ __align__(16) unsigned short h_sh[64 * 256]; // 32 KB

  const int tid = threadIdx.x;
  const int wave = tid >> 6;
  const int lane = tid & 63;
  const int l15 = lane & 15;
  const int q = lane >> 4; // quad 0..3
  const int row0 = blockIdx.x * 64;

  // ---- stage z tile [64 x 256] f32 -> bf16 blocked layout ----
  #pragma unroll
  for (int it = 0; it < 8; ++it) {
    int id = it * 256 + tid;
    int m = id >> 5;  // row 0..63
    int o = id & 31;  // octet of 8 floats
    const float* gp = z + (size_t)(row0 + m) * D_N + o * 8;
    f32x4 a = *(const f32x4*)gp;
    f32x4 b = *(const f32x4*)(gp + 4);
    u16x8 v;
    v[0] = f2bf(a[0]); v[1] = f2bf(a[1]); v[2] = f2bf(a[2]); v[3] = f2bf(a[3]);
    v[4] = f2bf(b[0]); v[5] = f2bf(b[1]); v[6] = f2bf(b[2]); v[7] = f2bf(b[3]);
    int slot = (((o >> 2) * 4 + (m >> 4)) * 64 + (o & 3) * 16 + (m & 15));
    *(u16x8*)(z_sh + slot * 8) = v;
  }
  __syncthreads();

  f32x4 acc2[4][4]; // dz accumulator
  #pragma unroll
  for (int a = 0; a < 4; ++a)
    #pragma unroll
    for (int b = 0; b < 4; ++b)
      acc2[a][b] = (f32x4){0.f, 0.f, 0.f, 0.f};
  float trp[4][4]; // trace partial per (tm, reg)
  #pragma unroll
  for (int a = 0; a < 4; ++a)
    #pragma unroll
    for (int r = 0; r < 4; ++r) trp[a][r] = 0.f;

  f32x4 accA[4][4], accB[4][4];

#define ZERO_ACC(A_)                                                          \
  _Pragma("unroll") for (int za_ = 0; za_ < 4; ++za_)                         \
  _Pragma("unroll") for (int zb_ = 0; zb_ < 4; ++zb_)                         \
    A_[za_][zb_] = (f32x4){0.f, 0.f, 0.f, 0.f};

#define G1_STEP(J0_, ACC_, S_) {                                              \
  bf16x8 afr_[4];                                                             \
  _Pragma("unroll") for (int tm_ = 0; tm_ < 4; ++tm_)                         \
    afr_[tm_] = *(const bf16x8*)(z_sh + (((S_) * 4 + tm_) * 64 + lane) * 8);  \
  bf16x8 bfr_[4];                                                             \
  _Pragma("unroll") for (int tn_ = 0; tn_ < 4; ++tn_)                         \
    bfr_[tn_] = *(const bf16x8*)(W1b +                                        \
        (size_t)((J0_) + wave * 64 + tn_ * 16 + l15) * D_N + (S_) * 32 + q * 8); \
  _Pragma("unroll") for (int tm_ = 0; tm_ < 4; ++tm_)                         \
  _Pragma("unroll") for (int tn_ = 0; tn_ < 4; ++tn_)                         \
    ACC_[tm_][tn_] = __builtin_amdgcn_mfma_f32_16x16x32_bf16(                 \
        afr_[tm_], bfr_[tn_], ACC_[tm_][tn_], 0, 0, 0);                       \
}

#define EPI_PRELOAD(J0_)                                                      \
  float b1c_[4], Mc_[4];                                                      \
  _Pragma("unroll") for (int tn_ = 0; tn_ < 4; ++tn_) {                       \
    int jg_ = (J0_) + wave * 64 + tn_ * 16 + l15;                             \
    b1c_[tn_] = b1[jg_];                                                      \
    Mc_[tn_] = M[jg_];                                                        \
  }

// piece S_ of 8: tn = S_>>1, tm in {(S_&1)*2, (S_&1)*2+1}, r 0..3 (8 elems)
#define EPI_STEP(ACC_, S_) {                                                  \
  const int etn_ = (S_) >> 1;                                                 \
  const int jl_ = wave * 64 + etn_ * 16 + l15;                                \
  const int slot_base_ = ((jl_ >> 5) * 4) * 64 + ((jl_ >> 3) & 3) * 16;       \
  const int byte_lo_ = jl_ & 7;                                               \
  const float b1v_ = b1c_[etn_];                                              \
  const float Mv_ = Mc_[etn_];                                                \
  _Pragma("unroll") for (int tt_ = 0; tt_ < 2; ++tt_) {                       \
    const int etm_ = ((S_) & 1) * 2 + tt_;                                    \
    _Pragma("unroll") for (int r_ = 0; r_ < 4; ++r_) {                        \
      float x_ = ACC_[etm_][etn_][r_] + b1v_;                                 \
      float e_ = __expf(-fabsf(x_));                                          \
      float inv_ = __builtin_amdgcn_rcpf(1.0f + e_);                          \
      float sig_ = (x_ >= 0.f) ? inv_ : (1.0f - inv_);                        \
      float sp_ = fmaxf(x_, 0.f) + __logf(1.0f + e_);                         \
      trp[etm_][r_] += sig_ * Mv_;                                            \
      int slot_ = slot_base_ + etm_ * 64 + (q * 4 + r_);                      \
      h_sh[slot_ * 8 + byte_lo_] = f2bf(sp_);                                 \
    }                                                                         \
  }                                                                           \
}

// epilogue(chunk @J0E_ from ACCE_) interleaved with GEMM1(chunk @J0G_ -> ACCG_)
#define MIX_FULL(J0E_, ACCE_, J0G_, ACCG_) {                                  \
  EPI_PRELOAD(J0E_);                                                          \
  ZERO_ACC(ACCG_);                                                            \
  _Pragma("unroll") for (int s_ = 0; s_ < 8; ++s_) {                          \
    G1_STEP(J0G_, ACCG_, s_);                                                 \
    EPI_STEP(ACCE_, s_);                                                      \
  }                                                                           \
}

#define EPI_ONLY(J0E_, ACCE_) {                                               \
  EPI_PRELOAD(J0E_);                                                          \
  _Pragma("unroll") for (int s_ = 0; s_ < 8; ++s_) {                          \
    EPI_STEP(ACCE_, s_);                                                      \
  }                                                                           \
}

#define G2_CHUNK(J0_) {                                                       \
  __builtin_amdgcn_s_setprio(1);                                              \
  _Pragma("unroll") for (int ks_ = 0; ks_ < 8; ++ks_) {                       \
    bf16x8 afr_[4];                                                           \
    _Pragma("unroll") for (int tm_ = 0; tm_ < 4; ++tm_)                       \
      afr_[tm_] = *(const bf16x8*)(h_sh + ((ks_ * 4 + tm_) * 64 + lane) * 8); \
    bf16x8 bfr_[4];                                                           \
    _Pragma("unroll") for (int tn_ = 0; tn_ < 4; ++tn_)                       \
      bfr_[tn_] = *(const bf16x8*)(W2b +                                      \
          (size_t)(wave * 64 + tn_ * 16 + l15) * W_N + (J0_) + ks_ * 32 + q * 8); \
    _Pragma("unroll") for (int tm_ = 0; tm_ < 4; ++tm_)                       \
    _Pragma("unroll") for (int tn_ = 0; tn_ < 4; ++tn_)                       \
      acc2[tm_][tn_] = __builtin_amdgcn_mfma_f32_16x16x32_bf16(               \
          afr_[tm_], bfr_[tn_], acc2[tm_][tn_], 0, 0, 0);                     \
  }                                                                           \
  __builtin_amdgcn_s_setprio(0);                                              \
}

  // ---- prologue: GEMM1 chunk 0 -> accA ----
  ZERO_ACC(accA);
  #pragma unroll
  for (int s = 0; s < 8; ++s) { G1_STEP(0, accA, s); }

  // ---- pipelined main loop: 4 chunks, unrolled by 2 for static A/B swap ----
  #pragma unroll 1
  for (int cc = 0; cc < 2; ++cc) {
    const int j0_0 = cc * 512;       // chunk 2cc
    const int j0_1 = j0_0 + 256;     // chunk 2cc+1

    // half A: epi(chunk 2cc from accA)  ||  GEMM1(chunk 2cc+1 -> accB)
    MIX_FULL(j0_0, accA, j0_1, accB);
    __syncthreads();                 // h_sh(2cc) ready
    G2_CHUNK(j0_0);
    __syncthreads();                 // h_sh(2cc) consumed

    // half B: epi(chunk 2cc+1 from accB)  ||  GEMM1(chunk 2cc+2 -> accA)
    if (cc == 0) {
      MIX_FULL(j0_1, accB, 512, accA);
    } else {
      EPI_ONLY(j0_1, accB);
    }
    __syncthreads();                 // h_sh(2cc+1) ready
    G2_CHUNK(j0_1);
    __syncthreads();                 // h_sh(2cc+1) consumed
  }

  // ---- store dz ----
  #pragma unroll
  for (int tm = 0; tm < 4; ++tm)
    #pragma unroll
    for (int tn = 0; tn < 4; ++tn)
      #pragma unroll
      for (int r = 0; r < 4; ++r)
        dz[(size_t)(row0 + tm * 16 + q * 4 + r) * D_N + wave * 64 + tn * 16 + l15] =
            acc2[tm][tn][r];

  // ---- trace: reduce across the 16 lanes of each quad, atomicAdd -sum ----
  #pragma unroll
  for (int tm = 0; tm < 4; ++tm) {
    #pragma unroll
    for (int r = 0; r < 4; ++r) {
      float v = trp[tm][r];
      v += __shfl_xor(v, 1);
      v += __shfl_xor(v, 2);
      v += __shfl_xor(v, 4);
      v += __shfl_xor(v, 8);
      if (l15 == 0) atomicAdd(tr + row0 + tm * 16 + q * 4 + r, -v);
    }
  }
}

extern "C" void kernel_launch(void* const* d_in, const int* in_sizes, int n_in,
                              void* d_out, int out_size, void* d_ws, size_t ws_size,
                              hipStream_t stream) {
  (void)in_sizes; (void)n_in; (void)out_size; (void)ws_size;
  // inputs: t[1], z[B,D], W1[W,D], b1[W], W2[D,W]  (all f32)
  const float* z  = (const float*)d_in[1];
  const float* W1 = (const float*)d_in[2];
  const float* b1 = (const float*)d_in[3];
  const float* W2 = (const float*)d_in[4];
  float* dz = (float*)d_out;                    // [B, D]
  float* tr = dz + (size_t)B_N * D_N;           // [B] = dlogpz_dt (negated trace)

  unsigned short* W1b = (unsigned short*)d_ws;  // 512 KB
  unsigned short* W2b = W1b + (size_t)W_N * D_N; // 512 KB
  float* M = (float*)(W2b + (size_t)W_N * D_N);  // 4 KB

  hipMemsetAsync(tr, 0, B_N * sizeof(float), stream);
  prep_kernel<<<dim3(W_N), dim3(256), 0, stream>>>(W1, W2, W1b, W2b, M);
  flow_kernel<<<dim3(B_N / 64), dim3(256), 0, stream>>>(z, b1, W1b, W2b, M, dz, tr);
}

// Round 2
// 255.312 us; speedup vs baseline: 1.2074x; 1.2074x over previous
//
#include <hip/hip_runtime.h>
#include <cstdint>
#include <cstddef>

// Problem constants
#define B_N 65536
#define D_N 256
#define W_N 1024

typedef __bf16 bf16x8 __attribute__((ext_vector_type(8)));
typedef float f32x4 __attribute__((ext_vector_type(4)));
typedef unsigned short u16x8 __attribute__((ext_vector_type(8)));

__device__ __forceinline__ unsigned short f2bf(float f) {
  // round-to-nearest-even f32 -> bf16 (no NaN in this problem)
  unsigned u = __float_as_uint(f);
  u += 0x7fffu + ((u >> 16) & 1u);
  return (unsigned short)(u >> 16);
}

// Raw barrier that does NOT drain vmcnt (preserves in-flight global loads).
// LDS hazards are covered by lgkmcnt(0); sched_barrier(0) stops hoisting.
__device__ __forceinline__ void lds_barrier() {
  __builtin_amdgcn_sched_barrier(0);
  asm volatile("s_waitcnt lgkmcnt(0)" ::: "memory");
  __builtin_amdgcn_s_barrier();
  __builtin_amdgcn_sched_barrier(0);
}

// ---------------------------------------------------------------------------
// Prep: cast W1 [1024x256] and W2 [256x1024] to bf16; M[j] = sum_i W1[j,i]*W2[i,j]
// ---------------------------------------------------------------------------
__global__ __launch_bounds__(256) void prep_kernel(
    const float* __restrict__ W1, const float* __restrict__ W2,
    unsigned short* __restrict__ W1b, unsigned short* __restrict__ W2b,
    float* __restrict__ M) {
  const int j = blockIdx.x;    // 0..1023
  const int t = threadIdx.x;   // 0..255
  const int gid = j * 256 + t; // covers 262144 exactly
  float w1 = W1[gid];
  float w2g = W2[gid];
  W1b[gid] = f2bf(w1);
  W2b[gid] = f2bf(w2g);
  // M[j]: thread t contributes W1[j,t] * W2[t,j]
  float p = w1 * W2[t * W_N + j];
  #pragma unroll
  for (int m = 32; m; m >>= 1) p += __shfl_xor(p, m);
  __shared__ float red[4];
  if ((t & 63) == 0) red[t >> 6] = p;
  __syncthreads();
  if (t == 0) M[j] = red[0] + red[1] + red[2] + red[3];
}

// ---------------------------------------------------------------------------
// Fused flow kernel. Round-0 phase structure (single acc1, 2 barriers/chunk)
// + explicit 3-deep register pipeline on the B-operand global loads of both
// GEMMs (the round-0 bottleneck: latency-serialized L2 loads), + raw barriers
// that keep those loads in flight across the epilogue.
// ---------------------------------------------------------------------------
__global__ __launch_bounds__(256, 2) void flow_kernel(
    const float* __restrict__ z, const float* __restrict__ b1,
    const unsigned short* __restrict__ W1b, const unsigned short* __restrict__ W2b,
    const float* __restrict__ M, float* __restrict__ dz, float* __restrict__ tr) {
  __shared__ __align__(16) unsigned short z_sh[64 * 256]; // 32 KB
  __shared__ __align__(16) unsigned short h_sh[64 * 256]; // 32 KB

  const int tid = threadIdx.x;
  const int wave = tid >> 6;
  const int lane = tid & 63;
  const int l15 = lane & 15;
  const int q = lane >> 4; // quad 0..3
  const int row0 = blockIdx.x * 64;

  // ---- stage z tile [64 x 256] f32 -> bf16 blocked layout ----
  #pragma unroll
  for (int it = 0; it < 8; ++it) {
    int id = it * 256 + tid;
    int m = id >> 5;  // row 0..63
    int o = id & 31;  // octet of 8 floats
    const float* gp = z + (size_t)(row0 + m) * D_N + o * 8;
    f32x4 a = *(const f32x4*)gp;
    f32x4 b = *(const f32x4*)(gp + 4);
    u16x8 v;
    v[0] = f2bf(a[0]); v[1] = f2bf(a[1]); v[2] = f2bf(a[2]); v[3] = f2bf(a[3]);
    v[4] = f2bf(b[0]); v[5] = f2bf(b[1]); v[6] = f2bf(b[2]); v[7] = f2bf(b[3]);
    int slot = (((o >> 2) * 4 + (m >> 4)) * 64 + (o & 3) * 16 + (m & 15));
    *(u16x8*)(z_sh + slot * 8) = v;
  }
  __syncthreads();

  f32x4 acc2[4][4]; // dz accumulator (AGPR, 64)
  #pragma unroll
  for (int a = 0; a < 4; ++a)
    #pragma unroll
    for (int b = 0; b < 4; ++b)
      acc2[a][b] = (f32x4){0.f, 0.f, 0.f, 0.f};
  float trp[4][4]; // trace partial per (tm, reg)
  #pragma unroll
  for (int a = 0; a < 4; ++a)
    #pragma unroll
    for (int r = 0; r < 4; ++r) trp[a][r] = 0.f;

  #pragma unroll 1
  for (int c = 0; c < 4; ++c) {
    const int j0 = c * 256;

    // Per-tn base pointers (ks walks via immediate offsets)
    const unsigned short* w1p[4];
    #pragma unroll
    for (int tn = 0; tn < 4; ++tn)
      w1p[tn] = W1b + (size_t)(j0 + wave * 64 + tn * 16 + l15) * D_N + q * 8;

    // ---- GEMM1 B pipeline: preissue ks = 0,1,2 into 3 register sets ----
    bf16x8 bq[3][4];
    #pragma unroll
    for (int p = 0; p < 3; ++p)
      #pragma unroll
      for (int tn = 0; tn < 4; ++tn)
        bq[p][tn] = *(const bf16x8*)(w1p[tn] + p * 32);

    // Preload epilogue constants under GEMM1 latency
    float b1c[4], Mc[4];
    #pragma unroll
    for (int tn = 0; tn < 4; ++tn) {
      int jg = j0 + wave * 64 + tn * 16 + l15;
      b1c[tn] = b1[jg];
      Mc[tn] = M[jg];
    }

    f32x4 acc1[4][4];
    #pragma unroll
    for (int a = 0; a < 4; ++a)
      #pragma unroll
      for (int b = 0; b < 4; ++b)
        acc1[a][b] = (f32x4){0.f, 0.f, 0.f, 0.f};

    // ---- GEMM1: pre[64 x 256chunk] = z_tile @ W1[j0+..]^T, K = 256 ----
    #pragma unroll
    for (int ks = 0; ks < 8; ++ks) {
      bf16x8 afr[4];
      #pragma unroll
      for (int tm = 0; tm < 4; ++tm)
        afr[tm] = *(const bf16x8*)(z_sh + ((ks * 4 + tm) * 64 + lane) * 8);
      #pragma unroll
      for (int tm = 0; tm < 4; ++tm)
        #pragma unroll
        for (int tn = 0; tn < 4; ++tn)
          acc1[tm][tn] = __builtin_amdgcn_mfma_f32_16x16x32_bf16(
              afr[tm], bq[ks % 3][tn], acc1[tm][tn], 0, 0, 0);
      if (ks < 5) { // reload this set for step ks+3
        #pragma unroll
        for (int tn = 0; tn < 4; ++tn)
          bq[ks % 3][tn] = *(const bf16x8*)(w1p[tn] + (ks + 3) * 32);
      }
    }

    // ---- preissue GEMM2 B sets 0..2 (latency hides under epilogue) ----
    const unsigned short* w2p[4];
    #pragma unroll
    for (int tn = 0; tn < 4; ++tn)
      w2p[tn] = W2b + (size_t)(wave * 64 + tn * 16 + l15) * W_N + j0 + q * 8;
    bf16x8 cq[3][4];
    #pragma unroll
    for (int p = 0; p < 3; ++p)
      #pragma unroll
      for (int tn = 0; tn < 4; ++tn)
        cq[p][tn] = *(const bf16x8*)(w2p[tn] + p * 32);

    lds_barrier(); // all waves done reading h_sh in previous chunk's GEMM2

    // ---- epilogue: softplus -> h_sh (blocked layout), sigmoid*M -> trace ----
    #pragma unroll
    for (int tn = 0; tn < 4; ++tn) {
      const int jl = wave * 64 + tn * 16 + l15; // chunk-local j, 0..255
      const float b1v = b1c[tn];
      const float Mv = Mc[tn];
      const int slot_base = ((jl >> 5) * 4) * 64 + ((jl >> 3) & 3) * 16;
      const int byte_lo = (jl & 7);
      #pragma unroll
      for (int tm = 0; tm < 4; ++tm) {
        #pragma unroll
        for (int r = 0; r < 4; ++r) {
          float x = acc1[tm][tn][r] + b1v;
          float e = __expf(-fabsf(x));
          float inv = __builtin_amdgcn_rcpf(1.0f + e);
          float sig = (x >= 0.f) ? inv : (1.0f - inv);
          float sp = fmaxf(x, 0.f) + __logf(1.0f + e);
          trp[tm][r] += sig * Mv;
          int slot = slot_base + tm * 64 + (q * 4 + r); // row = tm*16 + q*4 + r
          h_sh[slot * 8 + byte_lo] = f2bf(sp);
        }
      }
    }

    lds_barrier(); // h_sh ready

    // ---- GEMM2: dz += h_chunk[64 x 256] @ W2[:, j0+..]^T, K = 256 ----
    #pragma unroll
    for (int ks = 0; ks < 8; ++ks) {
      bf16x8 afr[4];
      #pragma unroll
      for (int tm = 0; tm < 4; ++tm)
        afr[tm] = *(const bf16x8*)(h_sh + ((ks * 4 + tm) * 64 + lane) * 8);
      #pragma unroll
      for (int tm = 0; tm < 4; ++tm)
        #pragma unroll
        for (int tn = 0; tn < 4; ++tn)
          acc2[tm][tn] = __builtin_amdgcn_mfma_f32_16x16x32_bf16(
              afr[tm], cq[ks % 3][tn], acc2[tm][tn], 0, 0, 0);
      if (ks < 5) { // reload this set for step ks+3
        #pragma unroll
        for (int tn = 0; tn < 4; ++tn)
          cq[ks % 3][tn] = *(const bf16x8*)(w2p[tn] + (ks + 3) * 32);
      }
    }
  }

  // ---- store dz ----
  #pragma unroll
  for (int tm = 0; tm < 4; ++tm)
    #pragma unroll
    for (int tn = 0; tn < 4; ++tn)
      #pragma unroll
      for (int r = 0; r < 4; ++r)
        dz[(size_t)(row0 + tm * 16 + q * 4 + r) * D_N + wave * 64 + tn * 16 + l15] =
            acc2[tm][tn][r];

  // ---- trace: reduce across the 16 lanes of each quad, atomicAdd -sum ----
  #pragma unroll
  for (int tm = 0; tm < 4; ++tm) {
    #pragma unroll
    for (int r = 0; r < 4; ++r) {
      float v = trp[tm][r];
      v += __shfl_xor(v, 1);
      v += __shfl_xor(v, 2);
      v += __shfl_xor(v, 4);
      v += __shfl_xor(v, 8);
      if (l15 == 0) atomicAdd(tr + row0 + tm * 16 + q * 4 + r, -v);
    }
  }
}

extern "C" void kernel_launch(void* const* d_in, const int* in_sizes, int n_in,
                              void* d_out, int out_size, void* d_ws, size_t ws_size,
                              hipStream_t stream) {
  (void)in_sizes; (void)n_in; (void)out_size; (void)ws_size;
  // inputs: t[1], z[B,D], W1[W,D], b1[W], W2[D,W]  (all f32)
  const float* z  = (const float*)d_in[1];
  const float* W1 = (const float*)d_in[2];
  const float* b1 = (const float*)d_in[3];
  const float* W2 = (const float*)d_in[4];
  float* dz = (float*)d_out;                    // [B, D]
  float* tr = dz + (size_t)B_N * D_N;           // [B] = dlogpz_dt (negated trace)

  unsigned short* W1b = (unsigned short*)d_ws;  // 512 KB
  unsigned short* W2b = W1b + (size_t)W_N * D_N; // 512 KB
  float* M = (float*)(W2b + (size_t)W_N * D_N);  // 4 KB

  hipMemsetAsync(tr, 0, B_N * sizeof(float), stream);
  prep_kernel<<<dim3(W_N), dim3(256), 0, stream>>>(W1, W2, W1b, W2b, M);
  flow_kernel<<<dim3(B_N / 64), dim3(256), 0, stream>>>(z, b1, W1b, W2b, M, dz, tr);
}